// Round 1
// baseline (1064.176 us; speedup 1.0000x reference)
//
#include <hip/hip_runtime.h>
#include <hip/hip_bf16.h>

// SparseMoE: B=4,S=2048 -> T=8192 tokens, D=1024, FF=4096, E=8, top-2.
// Pipeline: router(fp32) -> scan -> cvt/transpose weights to bf16 (k-contiguous)
// -> grouped GEMM1 (x@w1, relu, h bf16) -> grouped GEMM2 (h@w2, gate-scaled
// atomic scatter-add into out).
// Workspace: header(256B) + tok(256K) + gate(256K) + xb(16M) + w1T(64M) +
// w2T(64M) + h(128M) ~ 273 MB.

#define T_TOK 8192
#define D_EMB 1024
#define DFF   4096
#define N_EXP 8
#define BM 128
#define BN 128
#define BK 64

typedef __attribute__((ext_vector_type(8))) short bf16x8;
typedef __attribute__((ext_vector_type(4))) float floatx4;
typedef unsigned short bf16_t;

__device__ __forceinline__ bf16_t f2bf(float f) {
  union { float f; unsigned u; } a; a.f = f;
  unsigned u = a.u;
  return (bf16_t)((u + 0x7fffu + ((u >> 16) & 1u)) >> 16);  // RNE
}

// ---------------- cvt x -> bf16 ----------------
__global__ __launch_bounds__(256) void cvt_x_k(const float* __restrict__ x,
                                               bf16_t* __restrict__ xb) {
  int i = (blockIdx.x * 256 + threadIdx.x) * 4;
  float4 v = *(const float4*)(x + i);
  ushort4 o;
  o.x = f2bf(v.x); o.y = f2bf(v.y); o.z = f2bf(v.z); o.w = f2bf(v.w);
  *(ushort4*)(xb + i) = o;
}

// ------------- transpose+cvt: in [E][K][N] f32 -> out [E][N][K] bf16 -------------
__global__ __launch_bounds__(256) void tcvt_k(const float* __restrict__ in,
                                              bf16_t* __restrict__ outp,
                                              int K, int N) {
  __shared__ float tile[32][33];
  int e  = blockIdx.z;
  int n0 = blockIdx.x * 32;
  int k0 = blockIdx.y * 32;
  int tx = threadIdx.x;  // 0..31
  int ty = threadIdx.y;  // 0..7
  const float* src = in + (size_t)e * K * N;
#pragma unroll
  for (int l = 0; l < 32; l += 8)
    tile[ty + l][tx] = src[(size_t)(k0 + ty + l) * N + (n0 + tx)];
  __syncthreads();
  bf16_t* dst = outp + (size_t)e * K * N;
#pragma unroll
  for (int l = 0; l < 32; l += 8)
    dst[(size_t)(n0 + ty + l) * K + (k0 + tx)] = f2bf(tile[tx][ty + l]);
}

// ---------------- router ----------------
__global__ __launch_bounds__(256) void router_k(
    const float* __restrict__ x, const float* __restrict__ nu,
    const float* __restrict__ wg, const float* __restrict__ bgp,
    const float* __restrict__ wn, const float* __restrict__ bnp,
    int* __restrict__ cnt, int* __restrict__ tok, float* __restrict__ gate) {
  int t = blockIdx.x;
  int tid = threadIdx.x;
  float gl[8] = {0,0,0,0,0,0,0,0};
  float nl[8] = {0,0,0,0,0,0,0,0};
  const float* xr = x + (size_t)t * D_EMB;
  for (int i = tid; i < D_EMB; i += 256) {
    float xv = xr[i];
    float4 a0 = *(const float4*)(wg + i * 8);
    float4 a1 = *(const float4*)(wg + i * 8 + 4);
    float4 c0 = *(const float4*)(wn + i * 8);
    float4 c1 = *(const float4*)(wn + i * 8 + 4);
    gl[0] += xv * a0.x; gl[1] += xv * a0.y; gl[2] += xv * a0.z; gl[3] += xv * a0.w;
    gl[4] += xv * a1.x; gl[5] += xv * a1.y; gl[6] += xv * a1.z; gl[7] += xv * a1.w;
    nl[0] += xv * c0.x; nl[1] += xv * c0.y; nl[2] += xv * c0.z; nl[3] += xv * c0.w;
    nl[4] += xv * c1.x; nl[5] += xv * c1.y; nl[6] += xv * c1.z; nl[7] += xv * c1.w;
  }
  __shared__ float red[4][16];
  int lane = tid & 63;
  int wv = tid >> 6;
#pragma unroll
  for (int o = 0; o < 16; ++o) {
    float v = (o < 8) ? gl[o] : nl[o - 8];
#pragma unroll
    for (int s = 32; s > 0; s >>= 1) v += __shfl_down(v, s, 64);
    if (lane == 0) red[wv][o] = v;
  }
  __syncthreads();
  if (tid == 0) {
    float noisy[8];
#pragma unroll
    for (int e = 0; e < 8; ++e) {
      float lg = red[0][e] + red[1][e] + red[2][e] + red[3][e] + bgp[e];
      float nz = red[0][8 + e] + red[1][8 + e] + red[2][8 + e] + red[3][8 + e] + bnp[e];
      float sp = fmaxf(nz, 0.f) + log1pf(expf(-fabsf(nz)));  // stable softplus
      noisy[e] = lg + nu[(size_t)t * 8 + e] * sp;
    }
    int e1 = 0;
#pragma unroll
    for (int e = 1; e < 8; ++e) if (noisy[e] > noisy[e1]) e1 = e;
    int e2 = -1;
#pragma unroll
    for (int e = 0; e < 8; ++e) {
      if (e == e1) continue;
      if (e2 < 0 || noisy[e] > noisy[e2]) e2 = e;
    }
    float d = expf(noisy[e2] - noisy[e1]);   // <= 1, no overflow
    float g1 = 1.f / (1.f + d);
    float g2 = d / (1.f + d);
    int p1 = atomicAdd(&cnt[e1], 1);
    tok[e1 * T_TOK + p1] = t; gate[e1 * T_TOK + p1] = g1;
    int p2 = atomicAdd(&cnt[e2], 1);
    tok[e2 * T_TOK + p2] = t; gate[e2 * T_TOK + p2] = g2;
  }
}

// ---------------- scan (8 experts) ----------------
__global__ void scan_k(const int* __restrict__ cnt, int* __restrict__ offs) {
  if (threadIdx.x == 0 && blockIdx.x == 0) {
    int a = 0;
    for (int e = 0; e < N_EXP; ++e) { offs[e] = a; a += cnt[e]; }
    offs[N_EXP] = a;
  }
}

// ---------------- GEMM1: h = relu(x_gathered @ w1 + b1), bf16 out ----------------
__global__ __launch_bounds__(256) void gemm1_k(
    const bf16_t* __restrict__ xb, const bf16_t* __restrict__ w1T,
    const float* __restrict__ b1p, const int* __restrict__ cnt,
    const int* __restrict__ offs, const int* __restrict__ tok,
    bf16_t* __restrict__ h) {
  const int NT = DFF / BN;    // 32
  const int MT = T_TOK / BM;  // 64
  int bid = blockIdx.x;
  int e = bid / (MT * NT);
  int rem = bid % (MT * NT);
  int mt = rem / NT;
  int nt = rem % NT;
  int cnte = cnt[e];
  if (mt * BM >= cnte) return;
  int rows = min(BM, cnte - mt * BM);

  __shared__ bf16_t As[BM][BK + 8];
  __shared__ bf16_t Bs[BN][BK + 8];
  __shared__ int stok[BM];

  int tid = threadIdx.x;
  if (tid < BM) {
    int r = mt * BM + ((tid < rows) ? tid : 0);
    stok[tid] = tok[e * T_TOK + r];
  }
  __syncthreads();

  int lane = tid & 63;
  int wv = tid >> 6;
  int m0 = (wv & 1) * 64;
  int n0 = (wv >> 1) * 64;
  int lm = lane & 15;
  int lq = lane >> 4;

  floatx4 acc[4][4];
#pragma unroll
  for (int i = 0; i < 4; ++i)
#pragma unroll
    for (int j = 0; j < 4; ++j)
#pragma unroll
      for (int r = 0; r < 4; ++r) acc[i][j][r] = 0.f;

  int srow = tid >> 1;
  int soff = (tid & 1) * 32;
  size_t arow = (size_t)stok[srow] * D_EMB + soff;
  const bf16_t* wbase = w1T + ((size_t)e * DFF + nt * BN + srow) * D_EMB + soff;

  for (int kk = 0; kk < D_EMB; kk += BK) {
    const uint4* ga = (const uint4*)(xb + arow + kk);
    const uint4* gb = (const uint4*)(wbase + kk);
    uint4 a0 = ga[0], a1 = ga[1], a2 = ga[2], a3 = ga[3];
    uint4 b0 = gb[0], b1v = gb[1], b2v = gb[2], b3v = gb[3];
    uint4* la = (uint4*)&As[srow][soff];
    uint4* lb = (uint4*)&Bs[srow][soff];
    la[0] = a0; la[1] = a1; la[2] = a2; la[3] = a3;
    lb[0] = b0; lb[1] = b1v; lb[2] = b2v; lb[3] = b3v;
    __syncthreads();
#pragma unroll
    for (int ks = 0; ks < BK; ks += 32) {
      bf16x8 af[4], bfr[4];
#pragma unroll
      for (int i = 0; i < 4; ++i)
        af[i] = *(const bf16x8*)&As[m0 + i * 16 + lm][ks + lq * 8];
#pragma unroll
      for (int j = 0; j < 4; ++j)
        bfr[j] = *(const bf16x8*)&Bs[n0 + j * 16 + lm][ks + lq * 8];
#pragma unroll
      for (int i = 0; i < 4; ++i)
#pragma unroll
        for (int j = 0; j < 4; ++j)
          acc[i][j] = __builtin_amdgcn_mfma_f32_16x16x32_bf16(af[i], bfr[j], acc[i][j], 0, 0, 0);
    }
    __syncthreads();
  }

  int hbase = offs[e] + mt * BM;
#pragma unroll
  for (int i = 0; i < 4; ++i) {
    int lr0 = m0 + i * 16 + lq * 4;
#pragma unroll
    for (int r = 0; r < 4; ++r) {
      if (lr0 + r < rows) {
        size_t hrow = (size_t)(hbase + lr0 + r) * DFF;
#pragma unroll
        for (int j = 0; j < 4; ++j) {
          int col = nt * BN + n0 + j * 16 + lm;
          float v = acc[i][j][r] + b1p[e * DFF + col];
          h[hrow + col] = f2bf(fmaxf(v, 0.f));
        }
      }
    }
  }
}

// ---------------- GEMM2: out[tok] += gate * (h @ w2 + b2) ----------------
__global__ __launch_bounds__(256) void gemm2_k(
    const bf16_t* __restrict__ h, const bf16_t* __restrict__ w2T,
    const float* __restrict__ b2p, const int* __restrict__ cnt,
    const int* __restrict__ offs, const int* __restrict__ tok,
    const float* __restrict__ gate, float* __restrict__ out) {
  const int NT = D_EMB / BN;  // 8
  const int MT = T_TOK / BM;  // 64
  int bid = blockIdx.x;
  int e = bid / (MT * NT);
  int rem = bid % (MT * NT);
  int mt = rem / NT;
  int nt = rem % NT;
  int cnte = cnt[e];
  if (mt * BM >= cnte) return;
  int rows = min(BM, cnte - mt * BM);

  __shared__ bf16_t As[BM][BK + 8];
  __shared__ bf16_t Bs[BN][BK + 8];
  __shared__ int stok[BM];
  __shared__ float sgate[BM];

  int tid = threadIdx.x;
  if (tid < BM) {
    int idx = e * T_TOK + mt * BM + ((tid < rows) ? tid : 0);
    stok[tid] = tok[idx];
    sgate[tid] = gate[idx];
  }
  __syncthreads();

  int lane = tid & 63;
  int wv = tid >> 6;
  int m0 = (wv & 1) * 64;
  int n0 = (wv >> 1) * 64;
  int lm = lane & 15;
  int lq = lane >> 4;

  floatx4 acc[4][4];
#pragma unroll
  for (int i = 0; i < 4; ++i)
#pragma unroll
    for (int j = 0; j < 4; ++j)
#pragma unroll
      for (int r = 0; r < 4; ++r) acc[i][j][r] = 0.f;

  int srow = tid >> 1;
  int soff = (tid & 1) * 32;
  int srow_c = (srow < rows) ? srow : 0;  // don't read past expert's h region
  const bf16_t* abase = h + ((size_t)(offs[e] + mt * BM + srow_c)) * DFF + soff;
  const bf16_t* wbase = w2T + ((size_t)e * D_EMB + nt * BN + srow) * DFF + soff;

  for (int kk = 0; kk < DFF; kk += BK) {
    const uint4* ga = (const uint4*)(abase + kk);
    const uint4* gb = (const uint4*)(wbase + kk);
    uint4 a0 = ga[0], a1 = ga[1], a2 = ga[2], a3 = ga[3];
    uint4 b0 = gb[0], b1v = gb[1], b2v = gb[2], b3v = gb[3];
    uint4* la = (uint4*)&As[srow][soff];
    uint4* lb = (uint4*)&Bs[srow][soff];
    la[0] = a0; la[1] = a1; la[2] = a2; la[3] = a3;
    lb[0] = b0; lb[1] = b1v; lb[2] = b2v; lb[3] = b3v;
    __syncthreads();
#pragma unroll
    for (int ks = 0; ks < BK; ks += 32) {
      bf16x8 af[4], bfr[4];
#pragma unroll
      for (int i = 0; i < 4; ++i)
        af[i] = *(const bf16x8*)&As[m0 + i * 16 + lm][ks + lq * 8];
#pragma unroll
      for (int j = 0; j < 4; ++j)
        bfr[j] = *(const bf16x8*)&Bs[n0 + j * 16 + lm][ks + lq * 8];
#pragma unroll
      for (int i = 0; i < 4; ++i)
#pragma unroll
        for (int j = 0; j < 4; ++j)
          acc[i][j] = __builtin_amdgcn_mfma_f32_16x16x32_bf16(af[i], bfr[j], acc[i][j], 0, 0, 0);
    }
    __syncthreads();
  }

#pragma unroll
  for (int i = 0; i < 4; ++i) {
    int lr0 = m0 + i * 16 + lq * 4;
#pragma unroll
    for (int r = 0; r < 4; ++r) {
      int lr = lr0 + r;
      if (lr < rows) {
        int t = stok[lr];
        float g = sgate[lr];
#pragma unroll
        for (int j = 0; j < 4; ++j) {
          int col = nt * BN + n0 + j * 16 + lm;
          float v = g * (acc[i][j][r] + b2p[e * D_EMB + col]);
          unsafeAtomicAdd(&out[(size_t)t * D_EMB + col], v);
        }
      }
    }
  }
}

extern "C" void kernel_launch(void* const* d_in, const int* in_sizes, int n_in,
                              void* d_out, int out_size, void* d_ws, size_t ws_size,
                              hipStream_t stream) {
  const float* x  = (const float*)d_in[0];
  const float* nu = (const float*)d_in[1];
  const float* wg = (const float*)d_in[2];
  const float* bg = (const float*)d_in[3];
  const float* wn = (const float*)d_in[4];
  const float* bn = (const float*)d_in[5];
  const float* w1 = (const float*)d_in[6];
  const float* b1 = (const float*)d_in[7];
  const float* w2 = (const float*)d_in[8];
  const float* b2 = (const float*)d_in[9];
  float* out = (float*)d_out;

  char* ws = (char*)d_ws;
  size_t o = 0;
  int* cnt  = (int*)(ws + o);          // 8 ints
  int* offs = cnt + 8;                 // 9 ints (within 256B header)
  o += 256;
  int*   tok  = (int*)(ws + o);   o += (size_t)N_EXP * T_TOK * 4;
  float* gate = (float*)(ws + o); o += (size_t)N_EXP * T_TOK * 4;
  bf16_t* xb  = (bf16_t*)(ws + o); o += (size_t)T_TOK * D_EMB * 2;
  bf16_t* w1T = (bf16_t*)(ws + o); o += (size_t)N_EXP * D_EMB * DFF * 2;
  bf16_t* w2T = (bf16_t*)(ws + o); o += (size_t)N_EXP * D_EMB * DFF * 2;
  bf16_t* h   = (bf16_t*)(ws + o); o += (size_t)2 * T_TOK * DFF * 2;
  (void)o; (void)ws_size; (void)in_sizes; (void)n_in;

  hipMemsetAsync(cnt, 0, 256, stream);
  hipMemsetAsync(out, 0, (size_t)out_size * sizeof(float), stream);

  cvt_x_k<<<(T_TOK * D_EMB) / 1024, 256, 0, stream>>>(x, xb);
  tcvt_k<<<dim3(DFF / 32, D_EMB / 32, N_EXP), dim3(32, 8), 0, stream>>>(w1, w1T, D_EMB, DFF);
  tcvt_k<<<dim3(D_EMB / 32, DFF / 32, N_EXP), dim3(32, 8), 0, stream>>>(w2, w2T, DFF, D_EMB);
  router_k<<<T_TOK, 256, 0, stream>>>(x, nu, wg, bg, wn, bn, cnt, tok, gate);
  scan_k<<<1, 64, 0, stream>>>(cnt, offs);
  gemm1_k<<<N_EXP * (T_TOK / BM) * (DFF / BN), 256, 0, stream>>>(xb, w1T, b1, cnt, offs, tok, h);
  gemm2_k<<<N_EXP * (T_TOK / BM) * (D_EMB / BN), 256, 0, stream>>>(h, w2T, b2, cnt, offs, tok, gate, out);
}